// Round 12
// baseline (22089.917 us; speedup 1.0000x reference)
//
#include <hip/hip_runtime.h>

#define D 64
#define NPW 16  // nodes per wave in spmm
// Tile-phased SpMM: each row's edges are grouped by source tile (2^shift nodes,
// ~4 MB of y per tile). All spmm waves are co-resident (1407 blocks) and walk
// tiles in the same order, so the whole chip gathers from the same ~4 MB window
// at any instant -> every XCD's L2 caches the (replicated) window and gathers
// hit L2 instead of the Infinity Cache. Rows stay whole: 64 dims = 64 lanes,
// 4B/lane coalesced gathers. y-transform removes per-edge weights entirely.

static __device__ __forceinline__ float nt_loadf(const float* p) {
    return __builtin_nontemporal_load(p);
}
static __device__ __forceinline__ void nt_storef(float v, float* p) {
    __builtin_nontemporal_store(v, p);
}

// count per (dst, src-tile) cell; stride 8 (ntiles <= 7)
__global__ void deg2_kernel(const int* __restrict__ row, const int* __restrict__ col,
                            int* __restrict__ deg2, int E, int shift) {
    int e = blockIdx.x * blockDim.x + threadIdx.x;
    if (e < E) {
        int d = col[e];
        int t = row[e] >> shift;
        atomicAdd(&deg2[d * 8 + t], 1);
    }
}

// per-node degree totals + dinv
__global__ void rowprep_kernel(const int* __restrict__ deg2, int* __restrict__ deg,
                               float* __restrict__ dinv, int n) {
    int v = blockIdx.x * blockDim.x + threadIdx.x;
    if (v < n) {
        int s = 0;
#pragma unroll
        for (int t = 0; t < 8; ++t) s += deg2[v * 8 + t];
        deg[v] = s;
        dinv[v] = (s > 0) ? rsqrtf((float)s) : 0.0f;
    }
}

// Single-workgroup exclusive scan over N elements (runs once per call).
__global__ __launch_bounds__(1024) void scan_kernel(const int* __restrict__ deg,
                                                    int* __restrict__ row_ptr, int n) {
    __shared__ int wsum[16];
    const int tid = threadIdx.x;
    const int lane = tid & 63;
    const int w = tid >> 6;
    int carry = 0;
    for (int base = 0; base < n; base += 1024) {
        int i = base + tid;
        int v = (i < n) ? deg[i] : 0;
        int x = v;
#pragma unroll
        for (int off = 1; off < 64; off <<= 1) {
            int y = __shfl_up(x, off);
            if (lane >= off) x += y;
        }
        if (lane == 63) wsum[w] = x;
        __syncthreads();
        if (w == 0 && lane < 16) {
            int s = wsum[lane];
#pragma unroll
            for (int off = 1; off < 16; off <<= 1) {
                int y = __shfl_up(s, off);
                if (lane >= off) s += y;
            }
            wsum[lane] = s;
        }
        __syncthreads();
        int pref = (w > 0) ? wsum[w - 1] : 0;
        if (i < n) row_ptr[i] = carry + pref + (x - v);
        carry += wsum[15];
        __syncthreads();
    }
    if (tid == 0) row_ptr[n] = carry;
}

// absolute per-(node,tile) segment start pointers; entry [v*8+ntiles] = row end
__global__ void ptr2_kernel(const int* __restrict__ row_ptr, const int* __restrict__ deg2,
                            int* __restrict__ ptr2, int n, int ntiles) {
    int v = blockIdx.x * blockDim.x + threadIdx.x;
    if (v < n) {
        int run = row_ptr[v];
        for (int t = 0; t < ntiles; ++t) {
            ptr2[v * 8 + t] = run;
            run += deg2[v * 8 + t];
        }
        ptr2[v * 8 + ntiles] = run;
    }
}

// CSR build grouped by (dst, src-tile); only src ids (y-transform: no weights)
__global__ void scatter2_kernel(const int* __restrict__ row, const int* __restrict__ col,
                                const int* __restrict__ ptr2, int* __restrict__ cur2,
                                int* __restrict__ csr_src, int E, int shift) {
    int e = blockIdx.x * blockDim.x + threadIdx.x;
    if (e < E) {
        int s = row[e];
        int d = col[e];
        int t = s >> shift;
        int pos = ptr2[d * 8 + t] + atomicAdd(&cur2[d * 8 + t], 1);
        csr_src[pos] = s;
    }
}

// y0 = dinv ⊙ emb, acc0 = emb (both plain [node][64] layout; acc lives in d_out)
__global__ void init_kernel(const float4* __restrict__ emb, const float* __restrict__ dinv,
                            float4* __restrict__ y, float4* __restrict__ outAcc, int n) {
    int i = blockIdx.x * blockDim.x + threadIdx.x;   // over n*16 float4s
    if (i < n * 16) {
        int node = i >> 4;
        float dv = dinv[node];
        float4 v = emb[i];
        outAcc[i] = v;
        float4 yv;
        yv.x = v.x * dv; yv.y = v.y * dv; yv.z = v.z * dv; yv.w = v.w * dv;
        y[i] = yv;
    }
}

// One wave owns NPW consecutive dst nodes; lane = embedding dim. Outer loop over
// source tiles keeps the gather window ~4 MB chip-wide. Per-node accumulators
// stay in registers (i-loop fully unrolled -> static indexing). Edge loop
// unrolled 4x for 4 independent gathers in flight; csr/ptr2/dinv loads are
// wave-uniform (hardware broadcast). acc/y_out streams are nontemporal so they
// don't evict the resident tile window.
__global__ __launch_bounds__(256) void spmm2_kernel(
    const float* __restrict__ y_in, float* __restrict__ y_out,
    float* __restrict__ outAcc, const int* __restrict__ ptr2,
    const int* __restrict__ csr_src, const float* __restrict__ dinv,
    int n, int ntiles) {
    const int wave = (int)((blockIdx.x * 256 + threadIdx.x) >> 6);
    const int lane = threadIdx.x & 63;
    const int base = wave * NPW;
    if (base >= n) return;

    float acc[NPW];
#pragma unroll
    for (int i = 0; i < NPW; ++i) acc[i] = 0.f;

    for (int t = 0; t < ntiles; ++t) {
#pragma unroll
        for (int i = 0; i < NPW; ++i) {
            const int v = base + i;
            if (v < n) {
                int e = ptr2[v * 8 + t];
                const int e2 = ptr2[v * 8 + t + 1];
                float a = acc[i];
                for (; e + 3 < e2; e += 4) {
                    int s0 = csr_src[e];
                    int s1 = csr_src[e + 1];
                    int s2 = csr_src[e + 2];
                    int s3 = csr_src[e + 3];
                    float g0 = y_in[(size_t)s0 * D + lane];
                    float g1 = y_in[(size_t)s1 * D + lane];
                    float g2 = y_in[(size_t)s2 * D + lane];
                    float g3 = y_in[(size_t)s3 * D + lane];
                    a += g0; a += g1; a += g2; a += g3;
                }
                for (; e < e2; ++e)
                    a += y_in[(size_t)csr_src[e] * D + lane];
                acc[i] = a;
            }
        }
    }

#pragma unroll
    for (int i = 0; i < NPW; ++i) {
        const int v = base + i;
        if (v < n) {
            const float dv = dinv[v];
            const float xn = dv * acc[i];          // x_{l+1}
            const size_t o = (size_t)v * D + lane;
            nt_storef(nt_loadf(&outAcc[o]) + xn, &outAcc[o]);   // acc += x_{l+1}
            nt_storef(dv * xn, &y_out[o]);                      // y_{l+1}
        }
    }
}

__global__ void scale_kernel(float4* __restrict__ out, float f, int n4) {
    int i = blockIdx.x * blockDim.x + threadIdx.x;
    if (i < n4) {
        float4 a = out[i];
        a.x *= f; a.y *= f; a.z *= f; a.w *= f;
        out[i] = a;
    }
}

extern "C" void kernel_launch(void* const* d_in, const int* in_sizes, int n_in,
                              void* d_out, int out_size, void* d_ws, size_t ws_size,
                              hipStream_t stream) {
    const float* emb = (const float*)d_in[0];
    const int* eidx = (const int*)d_in[1];
    const int N = in_sizes[0] / D;   // 90000
    const int E = in_sizes[1] / 2;   // 3000000
    const int L = 100;
    const int* row = eidx;       // edge_index[0]
    const int* col = eidx + E;   // edge_index[1]

    // tile shift: 2^14 nodes = 4 MB of y per tile; ntiles must fit stride 8
    int shift = 14;
    while ((((N - 1) >> shift) + 1) > 7) ++shift;
    const int ntiles = ((N - 1) >> shift) + 1;   // 6 for N=90000

    size_t off = 0;
    auto alloc = [&](size_t bytes) -> void* {
        void* p = (char*)d_ws + off;
        off += (bytes + 255) & ~(size_t)255;
        return p;
    };
    int*   deg     = (int*)alloc((size_t)N * 4);
    float* dinv    = (float*)alloc((size_t)N * 4);
    int*   row_ptr = (int*)alloc((size_t)(N + 1) * 4);
    int*   deg2    = (int*)alloc((size_t)N * 8 * 4);
    int*   cur2    = (int*)alloc((size_t)N * 8 * 4);
    int*   ptr2    = (int*)alloc((size_t)N * 8 * 4);
    int*   csr_src = (int*)alloc((size_t)E * 4);
    float* yA      = (float*)alloc((size_t)N * D * 4);
    float* yB      = (float*)alloc((size_t)N * D * 4);

    (void)hipMemsetAsync(deg2, 0, (size_t)N * 8 * 4, stream);
    (void)hipMemsetAsync(cur2, 0, (size_t)N * 8 * 4, stream);

    deg2_kernel<<<(E + 255) / 256, 256, 0, stream>>>(row, col, deg2, E, shift);
    rowprep_kernel<<<(N + 255) / 256, 256, 0, stream>>>(deg2, deg, dinv, N);
    scan_kernel<<<1, 1024, 0, stream>>>(deg, row_ptr, N);
    ptr2_kernel<<<(N + 255) / 256, 256, 0, stream>>>(row_ptr, deg2, ptr2, N, ntiles);
    scatter2_kernel<<<(E + 255) / 256, 256, 0, stream>>>(row, col, ptr2, cur2, csr_src,
                                                         E, shift);

    float* out = (float*)d_out;
    init_kernel<<<(N * 16 + 255) / 256, 256, 0, stream>>>((const float4*)emb, dinv,
                                                          (float4*)yA, (float4*)out, N);

    const int spmm_blocks = (N + NPW * 4 - 1) / (NPW * 4);   // 1407: fully co-resident
    const float* yin = yA;
    float* yout = yB;
    for (int l = 0; l < L; ++l) {
        spmm2_kernel<<<spmm_blocks, 256, 0, stream>>>(yin, yout, out, ptr2, csr_src,
                                                      dinv, N, ntiles);
        const float* t = yin;
        yin = yout;
        yout = (float*)t;
    }

    const int n4 = N * D / 4;
    scale_kernel<<<(n4 + 255) / 256, 256, 0, stream>>>((float4*)out, 1.0f / (float)(L + 1), n4);
}

// Round 13
// 17480.579 us; speedup vs baseline: 1.2637x; 1.2637x over previous
//
#include <hip/hip_runtime.h>

#define D 64
#define NPW 16  // nodes per wave in spmm
// Tile-phased SpMM: edges grouped by (dst, src-tile); all spmm waves co-resident
// (1407 blocks) walk tiles in the same order, so the chip gathers from one ~4 MB
// window at a time -> window L2-resident per XCD (verified: FETCH 184 MB = 8x23).
// Round-12 lessons: NO nontemporal anywhere (nt pushed y/acc to HBM; window fills
// then cost ~184 us/layer of random HBM reads), and the edge walk must be
// node-PARALLEL (k-step all 16 segments in lockstep, two-phase loads) for ~16-deep
// MLP -- the node-serial walk was a bare latency chain (VALUBusy 19%, HBM 13%).

// count per (dst, src-tile) cell; stride 8 (ntiles <= 7)
__global__ void deg2_kernel(const int* __restrict__ row, const int* __restrict__ col,
                            int* __restrict__ deg2, int E, int shift) {
    int e = blockIdx.x * blockDim.x + threadIdx.x;
    if (e < E) {
        int d = col[e];
        int t = row[e] >> shift;
        atomicAdd(&deg2[d * 8 + t], 1);
    }
}

// per-node degree totals + dinv
__global__ void rowprep_kernel(const int* __restrict__ deg2, int* __restrict__ deg,
                               float* __restrict__ dinv, int n) {
    int v = blockIdx.x * blockDim.x + threadIdx.x;
    if (v < n) {
        int s = 0;
#pragma unroll
        for (int t = 0; t < 8; ++t) s += deg2[v * 8 + t];
        deg[v] = s;
        dinv[v] = (s > 0) ? rsqrtf((float)s) : 0.0f;
    }
}

// Single-workgroup exclusive scan over N elements (runs once per call).
__global__ __launch_bounds__(1024) void scan_kernel(const int* __restrict__ deg,
                                                    int* __restrict__ row_ptr, int n) {
    __shared__ int wsum[16];
    const int tid = threadIdx.x;
    const int lane = tid & 63;
    const int w = tid >> 6;
    int carry = 0;
    for (int base = 0; base < n; base += 1024) {
        int i = base + tid;
        int v = (i < n) ? deg[i] : 0;
        int x = v;
#pragma unroll
        for (int off = 1; off < 64; off <<= 1) {
            int y = __shfl_up(x, off);
            if (lane >= off) x += y;
        }
        if (lane == 63) wsum[w] = x;
        __syncthreads();
        if (w == 0 && lane < 16) {
            int s = wsum[lane];
#pragma unroll
            for (int off = 1; off < 16; off <<= 1) {
                int y = __shfl_up(s, off);
                if (lane >= off) s += y;
            }
            wsum[lane] = s;
        }
        __syncthreads();
        int pref = (w > 0) ? wsum[w - 1] : 0;
        if (i < n) row_ptr[i] = carry + pref + (x - v);
        carry += wsum[15];
        __syncthreads();
    }
    if (tid == 0) row_ptr[n] = carry;
}

// absolute per-(node,tile) segment start pointers; entry [v*8+ntiles] = row end
__global__ void ptr2_kernel(const int* __restrict__ row_ptr, const int* __restrict__ deg2,
                            int* __restrict__ ptr2, int n, int ntiles) {
    int v = blockIdx.x * blockDim.x + threadIdx.x;
    if (v < n) {
        int run = row_ptr[v];
        for (int t = 0; t < ntiles; ++t) {
            ptr2[v * 8 + t] = run;
            run += deg2[v * 8 + t];
        }
        ptr2[v * 8 + ntiles] = run;
    }
}

// CSR build grouped by (dst, src-tile); only src ids (y-transform: no weights)
__global__ void scatter2_kernel(const int* __restrict__ row, const int* __restrict__ col,
                                const int* __restrict__ ptr2, int* __restrict__ cur2,
                                int* __restrict__ csr_src, int E, int shift) {
    int e = blockIdx.x * blockDim.x + threadIdx.x;
    if (e < E) {
        int s = row[e];
        int d = col[e];
        int t = s >> shift;
        int pos = ptr2[d * 8 + t] + atomicAdd(&cur2[d * 8 + t], 1);
        csr_src[pos] = s;
    }
}

// y0 = dinv ⊙ emb, acc0 = emb (both plain [node][64] layout; acc lives in d_out)
__global__ void init_kernel(const float4* __restrict__ emb, const float* __restrict__ dinv,
                            float4* __restrict__ y, float4* __restrict__ outAcc, int n) {
    int i = blockIdx.x * blockDim.x + threadIdx.x;   // over n*16 float4s
    if (i < n * 16) {
        int node = i >> 4;
        float dv = dinv[node];
        float4 v = emb[i];
        outAcc[i] = v;
        float4 yv;
        yv.x = v.x * dv; yv.y = v.y * dv; yv.z = v.z * dv; yv.w = v.w * dv;
        y[i] = yv;
    }
}

// One wave owns NPW consecutive dst nodes; lane = embedding dim (coalesced 256B
// row gathers, wave-uniform address -> 1 request). Per tile, all NPW segments
// are marched in LOCKSTEP (k-loop to the wave-max length) with two-phase loads
// per step: 8 index loads -> 8 row gathers -> 8 masked adds (x2 chunks), giving
// deep MLP with zero divergent branches. Inactive slots re-load a hot line.
__global__ __launch_bounds__(256) void spmm2_kernel(
    const float* __restrict__ y_in, float* __restrict__ y_out,
    float* __restrict__ outAcc, const int* __restrict__ ptr2,
    const int* __restrict__ csr_src, const float* __restrict__ dinv,
    int n, int ntiles, int E) {
    const int wave = (int)((blockIdx.x * 256 + threadIdx.x) >> 6);
    const int lane = threadIdx.x & 63;
    const int base = wave * NPW;
    if (base >= n) return;
    const int Em1 = E - 1;

    float acc[NPW];
#pragma unroll
    for (int i = 0; i < NPW; ++i) acc[i] = 0.f;

    for (int t = 0; t < ntiles; ++t) {
        int sp[NPW], len[NPW];
#pragma unroll
        for (int i = 0; i < NPW; ++i) {
            const int v = base + i;
            int a = 0, b = 0;
            if (v < n) {
                a = ptr2[v * 8 + t];
                b = ptr2[v * 8 + t + 1];
            }
            sp[i] = a;
            len[i] = b - a;
        }
        int mx = 0;
#pragma unroll
        for (int i = 0; i < NPW; ++i) mx = (len[i] > mx) ? len[i] : mx;

        for (int k = 0; k < mx; ++k) {
            // chunk 0: nodes 0..7
            {
                int idx[8];
#pragma unroll
                for (int i = 0; i < 8; ++i) {
                    int e = sp[i] + ((k < len[i]) ? k : 0);
                    idx[i] = csr_src[(e < Em1) ? e : Em1];
                }
                float gv[8];
#pragma unroll
                for (int i = 0; i < 8; ++i)
                    gv[i] = y_in[(size_t)idx[i] * D + lane];
#pragma unroll
                for (int i = 0; i < 8; ++i)
                    acc[i] += (k < len[i]) ? gv[i] : 0.f;
            }
            // chunk 1: nodes 8..15
            {
                int idx[8];
#pragma unroll
                for (int i = 0; i < 8; ++i) {
                    int e = sp[i + 8] + ((k < len[i + 8]) ? k : 0);
                    idx[i] = csr_src[(e < Em1) ? e : Em1];
                }
                float gv[8];
#pragma unroll
                for (int i = 0; i < 8; ++i)
                    gv[i] = y_in[(size_t)idx[i] * D + lane];
#pragma unroll
                for (int i = 0; i < 8; ++i)
                    acc[i + 8] += (k < len[i + 8]) ? gv[i] : 0.f;
            }
        }
    }

#pragma unroll
    for (int i = 0; i < NPW; ++i) {
        const int v = base + i;
        if (v < n) {
            const float dv = dinv[v];
            const float xn = dv * acc[i];          // x_{l+1}
            const size_t o = (size_t)v * D + lane;
            outAcc[o] += xn;                       // acc += x_{l+1} (plain: L2/L3)
            y_out[o] = dv * xn;                    // y_{l+1}      (plain: L2/L3)
        }
    }
}

__global__ void scale_kernel(float4* __restrict__ out, float f, int n4) {
    int i = blockIdx.x * blockDim.x + threadIdx.x;
    if (i < n4) {
        float4 a = out[i];
        a.x *= f; a.y *= f; a.z *= f; a.w *= f;
        out[i] = a;
    }
}

extern "C" void kernel_launch(void* const* d_in, const int* in_sizes, int n_in,
                              void* d_out, int out_size, void* d_ws, size_t ws_size,
                              hipStream_t stream) {
    const float* emb = (const float*)d_in[0];
    const int* eidx = (const int*)d_in[1];
    const int N = in_sizes[0] / D;   // 90000
    const int E = in_sizes[1] / 2;   // 3000000
    const int L = 100;
    const int* row = eidx;       // edge_index[0]
    const int* col = eidx + E;   // edge_index[1]

    // tile shift: 2^14 nodes = 4 MB of y per tile; ntiles must fit stride 8
    int shift = 14;
    while ((((N - 1) >> shift) + 1) > 7) ++shift;
    const int ntiles = ((N - 1) >> shift) + 1;   // 6 for N=90000

    size_t off = 0;
    auto alloc = [&](size_t bytes) -> void* {
        void* p = (char*)d_ws + off;
        off += (bytes + 255) & ~(size_t)255;
        return p;
    };
    int*   deg     = (int*)alloc((size_t)N * 4);
    float* dinv    = (float*)alloc((size_t)N * 4);
    int*   row_ptr = (int*)alloc((size_t)(N + 1) * 4);
    int*   deg2    = (int*)alloc((size_t)N * 8 * 4);
    int*   cur2    = (int*)alloc((size_t)N * 8 * 4);
    int*   ptr2    = (int*)alloc((size_t)N * 8 * 4);
    int*   csr_src = (int*)alloc((size_t)E * 4);
    float* yA      = (float*)alloc((size_t)N * D * 4);
    float* yB      = (float*)alloc((size_t)N * D * 4);

    (void)hipMemsetAsync(deg2, 0, (size_t)N * 8 * 4, stream);
    (void)hipMemsetAsync(cur2, 0, (size_t)N * 8 * 4, stream);

    deg2_kernel<<<(E + 255) / 256, 256, 0, stream>>>(row, col, deg2, E, shift);
    rowprep_kernel<<<(N + 255) / 256, 256, 0, stream>>>(deg2, deg, dinv, N);
    scan_kernel<<<1, 1024, 0, stream>>>(deg, row_ptr, N);
    ptr2_kernel<<<(N + 255) / 256, 256, 0, stream>>>(row_ptr, deg2, ptr2, N, ntiles);
    scatter2_kernel<<<(E + 255) / 256, 256, 0, stream>>>(row, col, ptr2, cur2, csr_src,
                                                         E, shift);

    float* out = (float*)d_out;
    init_kernel<<<(N * 16 + 255) / 256, 256, 0, stream>>>((const float4*)emb, dinv,
                                                          (float4*)yA, (float4*)out, N);

    const int spmm_blocks = (N + NPW * 4 - 1) / (NPW * 4);   // 1407: fully co-resident
    const float* yin = yA;
    float* yout = yB;
    for (int l = 0; l < L; ++l) {
        spmm2_kernel<<<spmm_blocks, 256, 0, stream>>>(yin, yout, out, ptr2, csr_src,
                                                      dinv, N, ntiles, E);
        const float* t = yin;
        yin = yout;
        yout = (float*)t;
    }

    const int n4 = N * D / 4;
    scale_kernel<<<(n4 + 255) / 256, 256, 0, stream>>>((float4*)out, 1.0f / (float)(L + 1), n4);
}